// Round 1
// baseline (267.975 us; speedup 1.0000x reference)
//
#include <hip/hip_runtime.h>
#include <math.h>

#define BGR 64          // graphs
#define N0 512          // nodes/graph at level 1
#define E_TOT (BGR*N0*16)
#define EPG 8192        // edge slots per graph, fixed across levels
#define EIT 16          // EPG / 512 threads
#define HID 128

// ---- XCD heuristic: blockIdx % 8 -> XCD; graph g pinned to XCD g/8.

// Agent-scope (L1-bypassing) 8B load: required for same-kernel RAW reuse of
// csr/edges that this block rewrote earlier (plain loads could hit stale L1).
__device__ __forceinline__ int2 ldcoh(const int2* p){
  unsigned long long v = __hip_atomic_load(
      (const unsigned long long*)p, __ATOMIC_RELAXED, __HIP_MEMORY_SCOPE_AGENT);
  int2 r; r.x = (int)(unsigned int)v; r.y = (int)(unsigned int)(v >> 32);
  return r;
}

template<bool COH>
__device__ __forceinline__ int2 lde(const int2* p){
  if (COH) return ldcoh(p);
  return *p;
}

// scalar score-GCN edge sum (hloc in LDS)
template<bool COH>
__device__ __forceinline__ float score_edges(const int2* __restrict__ csr,
    int start, int c, const float* hloc, int gbase){
  float a = 0.f; int j = 0;
  for (; j + 4 <= c; j += 4){
    int2 e0 = lde<COH>(csr+start+j),   e1 = lde<COH>(csr+start+j+1);
    int2 e2 = lde<COH>(csr+start+j+2), e3 = lde<COH>(csr+start+j+3);
    a += __int_as_float(e0.y)*hloc[e0.x - gbase]
       + __int_as_float(e1.y)*hloc[e1.x - gbase]
       + __int_as_float(e2.y)*hloc[e2.x - gbase]
       + __int_as_float(e3.y)*hloc[e3.x - gbase];
  }
  for (; j < c; j++){
    int2 e = lde<COH>(csr+start+j);
    a += __int_as_float(e.y)*hloc[e.x - gbase];
  }
  return a;
}

// float4 GCN edge aggregation, h4 in LDS
__device__ __forceinline__ float4 row_edges_coh(const int2* __restrict__ csr,
    int start, int c, const float4* h4, int gbase, int l){
  float4 acc = make_float4(0.f,0.f,0.f,0.f);
  int j = 0;
  for (; j + 4 <= c; j += 4){
    int2 e0 = ldcoh(csr+start+j),   e1 = ldcoh(csr+start+j+1);
    int2 e2 = ldcoh(csr+start+j+2), e3 = ldcoh(csr+start+j+3);
    float4 h0 = h4[(e0.x - gbase)*32 + l];
    float4 h1 = h4[(e1.x - gbase)*32 + l];
    float4 h2 = h4[(e2.x - gbase)*32 + l];
    float4 h3 = h4[(e3.x - gbase)*32 + l];
    float w0 = __int_as_float(e0.y), w1 = __int_as_float(e1.y);
    float w2 = __int_as_float(e2.y), w3 = __int_as_float(e3.y);
    acc.x += w0*h0.x + w1*h1.x + w2*h2.x + w3*h3.x;
    acc.y += w0*h0.y + w1*h1.y + w2*h2.y + w3*h3.y;
    acc.z += w0*h0.z + w1*h1.z + w2*h2.z + w3*h3.z;
    acc.w += w0*h0.w + w1*h1.w + w2*h2.w + w3*h3.w;
  }
  for (; j < c; j++){
    int2 e = ldcoh(csr+start+j);
    float wgt = __int_as_float(e.y);
    float4 hv = h4[(e.x - gbase)*32 + l];
    acc.x += wgt*hv.x; acc.y += wgt*hv.y; acc.z += wgt*hv.z; acc.w += wgt*hv.w;
  }
  return acc;
}

// hybrid shfl/LDS bitonic (descending, idx tie-break) — verbatim from k_mega
__device__ __forceinline__ void bitonic_sort(float* sv, int* si, float v, int idx,
                                             int t, int nper, bool act){
  for (int kk = 2; kk <= nper; kk <<= 1){
    for (int jj = kk >> 1; jj > 0; jj >>= 1){
      if (jj >= 64){
        if (act){ sv[t] = v; si[t] = idx; }
        __syncthreads();
        if (act){
          int p = t ^ jj;
          float pv = sv[p]; int pi = si[p];
          bool amLower = (t & jj) == 0;
          bool dirDesc = (t & kk) == 0;
          bool betterMine = (v > pv) || (v == pv && idx < pi);
          if ((amLower == dirDesc) != betterMine){ v = pv; idx = pi; }
        }
        __syncthreads();
      } else if (act){
        float pv = __shfl_xor(v, jj);
        int   pi = __shfl_xor(idx, jj);
        bool amLower = (t & jj) == 0;
        bool dirDesc = (t & kk) == 0;
        bool betterMine = (v > pv) || (v == pv && idx < pi);
        if ((amLower == dirDesc) != betterMine){ v = pv; idx = pi; }
      }
    }
  }
  if (act){ sv[t] = v; si[t] = idx; }
  __syncthreads();
}

// relabel edges + degree + scan + CSR fill; topology (rpl/cntl/dl) -> LDS
template<bool COH>
__device__ __forceinline__ void relabel(int2* __restrict__ edges,
    int2* __restrict__ csr, const int* si, int* map, int* sb, int* cur,
    float* dl, int* rpl, int* cntl, int t, int nper, int k,
    int gbase, int ebase){
  if (t < nper) map[t] = -1;
  if (t < k) sb[t] = 0;
  __syncthreads();
  if (t < k) map[si[t]] = t;
  __syncthreads();
  int2 ebuf[EIT];
  #pragma unroll
  for (int it = 0; it < EIT; it++){
    int i = ebase + it*512 + t;
    int2 e = lde<COH>(edges + i);
    int2 ne = make_int2(-1, 0);
    if (e.x >= 0){
      int ns = map[e.x - gbase], nd = map[e.y - gbase];
      if (ns >= 0 && nd >= 0){
        ne = make_int2(gbase + ns, gbase + nd);
        atomicAdd(&sb[nd], 1);
      }
    }
    ebuf[it] = ne;
    edges[i] = ne;
  }
  __syncthreads();
  int vdeg = (t < k) ? sb[t] : 0;
  for (int off = 1; off < k; off <<= 1){
    int add = (t >= off && t < k) ? sb[t-off] : 0;
    __syncthreads();
    if (t < k) sb[t] += add;
    __syncthreads();
  }
  if (t < k){
    int excl = sb[t] - vdeg;
    rpl[t] = ebase + excl;
    cntl[t] = vdeg;
    cur[t] = excl;
    float dv = rsqrtf((float)vdeg + 1.f);
    dl[t] = dv;
  }
  __syncthreads();
  #pragma unroll
  for (int it = 0; it < EIT; it++){
    int2 e = ebuf[it];
    if (e.x >= 0){
      int sl = e.x - gbase, dc = e.y - gbase;
      int pos = atomicAdd(&cur[dc], 1);
      csr[ebase + pos] = make_int2(e.x, __float_as_int(dl[sl]*dl[dc]));
    }
  }
  __syncthreads();
}

// in-place h = x @ W over LDS rows; 64-node tiles, 16 outputs/thread.
// i-ascending accumulation == k_gemm16 order (bit-identical results).
__device__ __forceinline__ void gemm_inplace(float* xl, const float* __restrict__ W,
                                             int nn, int t){
  float4* xl4 = (float4*)xl;
  int fq = t & 31;          // output f = fq*4 .. fq*4+3
  int ng = t >> 5;          // node subgroup 0..15
  for (int tb = 0; tb < nn; tb += 64){
    int n0 = tb + ng*4;
    float4 acc[4];
    #pragma unroll
    for (int c = 0; c < 4; c++) acc[c] = make_float4(0.f,0.f,0.f,0.f);
    for (int i = 0; i < HID; i += 4){
      float4 w0 = *(const float4*)(W + (i+0)*HID + fq*4);
      float4 w1 = *(const float4*)(W + (i+1)*HID + fq*4);
      float4 w2 = *(const float4*)(W + (i+2)*HID + fq*4);
      float4 w3 = *(const float4*)(W + (i+3)*HID + fq*4);
      #pragma unroll
      for (int c = 0; c < 4; c++){
        float4 xv = *(const float4*)(xl + (n0+c)*HID + i);
        acc[c].x += xv.x*w0.x; acc[c].x += xv.y*w1.x;
        acc[c].x += xv.z*w2.x; acc[c].x += xv.w*w3.x;
        acc[c].y += xv.x*w0.y; acc[c].y += xv.y*w1.y;
        acc[c].y += xv.z*w2.y; acc[c].y += xv.w*w3.y;
        acc[c].z += xv.x*w0.z; acc[c].z += xv.y*w1.z;
        acc[c].z += xv.z*w2.z; acc[c].z += xv.w*w3.z;
        acc[c].w += xv.x*w0.w; acc[c].w += xv.y*w1.w;
        acc[c].w += xv.z*w2.w; acc[c].w += xv.w*w3.w;
      }
    }
    __syncthreads();           // all reads of this tile done before overwrite
    #pragma unroll
    for (int c = 0; c < 4; c++)
      xl4[(n0+c)*32 + fq] = acc[c];
  }
  __syncthreads();
}

// Per-graph level-1 topology (unchanged)
__global__ __launch_bounds__(512) void k_topo0(
    const int* __restrict__ s0, const int* __restrict__ d0,
    int2* __restrict__ edges, int* __restrict__ cnt, int* __restrict__ rowptr,
    float* __restrict__ dinv, int2* __restrict__ csr){
  __shared__ int   deg[512];
  __shared__ int   sb[512];
  __shared__ int   cur[512];
  __shared__ float dl[512];
  int g = (blockIdx.x & 7)*8 + (blockIdx.x >> 3);
  int t = threadIdx.x;
  int gbase = g*N0, ebase = g*EPG;
  deg[t] = 0;
  __syncthreads();
  int2 ebuf[EIT];
  #pragma unroll
  for (int it = 0; it < EIT; it++){
    int i = ebase + it*512 + t;
    int2 e = make_int2(s0[i], d0[i]);
    ebuf[it] = e;
    edges[i] = e;
    atomicAdd(&deg[e.y - gbase], 1);
  }
  __syncthreads();
  int vdeg = deg[t];
  sb[t] = vdeg; __syncthreads();
  for (int off = 1; off < 512; off <<= 1){
    int add = (t >= off) ? sb[t-off] : 0;
    __syncthreads(); sb[t] += add; __syncthreads();
  }
  int excl = sb[t] - vdeg;
  rowptr[gbase + t] = ebase + excl;
  cnt[gbase + t] = vdeg;
  cur[t] = excl;
  float dv = rsqrtf((float)vdeg + 1.f);
  dl[t] = dv;
  dinv[gbase + t] = dv;
  __syncthreads();
  #pragma unroll
  for (int it = 0; it < EIT; it++){
    int2 e = ebuf[it];
    int sl = e.x - gbase, dc = e.y - gbase;
    int pos = atomicAdd(&cur[dc], 1);
    csr[ebase + pos] = make_int2(e.x, __float_as_int(dl[sl]*dl[dc]));
  }
}

// Level-1 fused GEMM+gather (unchanged)
__global__ __launch_bounds__(512) void k_l1_fused(
    const float* __restrict__ x, const float* __restrict__ W1,
    const int2* __restrict__ csr, const int* __restrict__ rowptr,
    const int* __restrict__ cnt, const float* __restrict__ dinv,
    const float* __restrict__ b1, const float* __restrict__ Wp,
    float4* __restrict__ gout4, float* __restrict__ hp_part){
  extern __shared__ float hl[];   // 512 nodes x 32 feats = 64 KB
  int b = blockIdx.x;
  int xcd = b & 7, idx = b >> 3;
  int graph = xcd*8 + (idx >> 3);
  int sub = idx & 7;
  int qf = sub >> 1, half = sub & 1;
  int t = threadIdx.x;
  int gbase = graph*N0;
  int fp = t & 31;
  int f = qf*32 + fp;
  float wcol[10];
  #pragma unroll
  for (int k = 0; k < 10; k++) wcol[k] = W1[k*HID + f];
  for (int n = t >> 5; n < N0; n += 16){
    const float* xr = x + (gbase + n)*10;
    float acc = 0.f;
    #pragma unroll
    for (int k = 0; k < 10; k++) acc += xr[k]*wcol[k];
    hl[n*32 + fp] = acc;
  }
  __syncthreads();
  const float4* hl4 = (const float4*)hl;
  int l = t & 7, grp = t >> 3;
  float4 bb = ((const float4*)b1)[qf*8 + l];
  float4 wp = ((const float4*)Wp)[qf*8 + l];
  int n0 = half*256;
  for (int nl = n0 + grp; nl < n0 + 256; nl += 64){
    int node = gbase + nl;
    int start = rowptr[node], c = cnt[node];
    float4 acc = make_float4(0.f,0.f,0.f,0.f);
    int j = 0;
    for (; j + 4 <= c; j += 4){
      int2 e0 = csr[start+j],   e1 = csr[start+j+1];
      int2 e2 = csr[start+j+2], e3 = csr[start+j+3];
      float4 h0 = hl4[(e0.x - gbase)*8 + l];
      float4 h1 = hl4[(e1.x - gbase)*8 + l];
      float4 h2 = hl4[(e2.x - gbase)*8 + l];
      float4 h3 = hl4[(e3.x - gbase)*8 + l];
      float w0 = __int_as_float(e0.y), w1 = __int_as_float(e1.y);
      float w2 = __int_as_float(e2.y), w3 = __int_as_float(e3.y);
      acc.x += w0*h0.x + w1*h1.x + w2*h2.x + w3*h3.x;
      acc.y += w0*h0.y + w1*h1.y + w2*h2.y + w3*h3.y;
      acc.z += w0*h0.z + w1*h1.z + w2*h2.z + w3*h3.z;
      acc.w += w0*h0.w + w1*h1.w + w2*h2.w + w3*h3.w;
    }
    for (; j < c; j++){
      int2 e = csr[start + j];
      float wgt = __int_as_float(e.y);
      float4 hv = hl4[(e.x - gbase)*8 + l];
      acc.x += wgt*hv.x; acc.y += wgt*hv.y; acc.z += wgt*hv.z; acc.w += wgt*hv.w;
    }
    float di = dinv[node], dd = di*di;
    float4 hs = hl4[nl*8 + l];
    float4 v;
    v.x = fmaxf(acc.x + hs.x*dd + bb.x, 0.f);
    v.y = fmaxf(acc.y + hs.y*dd + bb.y, 0.f);
    v.z = fmaxf(acc.z + hs.z*dd + bb.z, 0.f);
    v.w = fmaxf(acc.w + hs.w*dd + bb.w, 0.f);
    gout4[node*32 + qf*8 + l] = v;
    float contrib = v.x*wp.x + v.y*wp.y + v.z*wp.z + v.w*wp.w;
    #pragma unroll
    for (int off = 4; off; off >>= 1) contrib += __shfl_down(contrib, off, 8);
    if (l == 0) hp_part[qf*32768 + node] = contrib;
  }
}

// Persistent per-graph tail: mega1 + (gemm+gather+mega)x2 + MLP, all in one
// block. x2/h2/x3/h3 live in LDS; gout2/gout3 are never materialized (score
// pass keeps only the Wp dot; selected rows are recomputed after top-k).
// Node-id base is g*512 at EVERY level so global edges/csr stay per-graph
// disjoint (no cross-block races); rowptr/cnt/dinv for levels 2/3 are LDS.
__global__ __launch_bounds__(512) void k_tail(
    const float4* __restrict__ gout4, const float* __restrict__ hp_part,
    int2* __restrict__ csr, int2* __restrict__ edges,
    const int* __restrict__ rowptr1, const int* __restrict__ cnt1,
    const float* __restrict__ dinv1, const float* __restrict__ bp,
    const float* __restrict__ W2, const float* __restrict__ b2,
    const float* __restrict__ W3, const float* __restrict__ b3,
    const float* __restrict__ Wp,
    const float* __restrict__ L1W, const float* __restrict__ L1b,
    const float* __restrict__ L2W, const float* __restrict__ L2b,
    float* __restrict__ out){
  __shared__ float xl[256*HID];           // 128 KB: x2/h2, then x3/h3
  __shared__ float sv[512];
  __shared__ int   si[512];
  __shared__ float hpl[512];
  __shared__ union UU {                   // relabel scratch vs pool partials
    struct { int map[512]; int sb[512]; int cur[256]; } r;
    float4 pr[2][16][32];                 // [0]=max, [1]=sum
  } u;
  __shared__ float dl[256];
  __shared__ int   rpl[256];
  __shared__ int   cntl[256];
  __shared__ float zacc[256];
  __shared__ float red[2];

  int g = (blockIdx.x & 7)*8 + (blockIdx.x >> 3);
  int t = threadIdx.x;
  int gbase = g*N0, ebase = g*EPG;
  int l = t & 31, j0 = t >> 5;
  float4* xl4 = (float4*)xl;
  float bp0 = bp[0];

  // ================= M1: level-1 mega (512 -> 256) =================
  {
    int node = gbase + t;
    hpl[t] = hp_part[node] + hp_part[32768 + node]
           + hp_part[65536 + node] + hp_part[98304 + node];
  }
  __syncthreads();
  {
    int start = rowptr1[gbase + t], c = cnt1[gbase + t];
    float a = score_edges<false>(csr, start, c, hpl, gbase);
    float di = dinv1[gbase + t];
    float v = tanhf(a + hpl[t]*di*di + bp0);
    bitonic_sort(sv, si, v, t, t, 512, true);
  }
  // pool 256 selected from global gout1 into LDS x2; readout -> zacc
  {
    float4 mx = make_float4(-INFINITY,-INFINITY,-INFINITY,-INFINITY);
    float4 sm = make_float4(0.f,0.f,0.f,0.f);
    for (int j = j0; j < 256; j += 16){
      float val = sv[j]; int row = si[j];
      float4 hv = gout4[(gbase + row)*32 + l];
      float4 o = make_float4(hv.x*val, hv.y*val, hv.z*val, hv.w*val);
      xl4[j*32 + l] = o;
      mx.x = fmaxf(mx.x, o.x); mx.y = fmaxf(mx.y, o.y);
      mx.z = fmaxf(mx.z, o.z); mx.w = fmaxf(mx.w, o.w);
      sm.x += o.x; sm.y += o.y; sm.z += o.z; sm.w += o.w;
    }
    u.pr[0][j0][l] = mx; u.pr[1][j0][l] = sm;
    __syncthreads();
    if (t < 32){
      float4 M = u.pr[0][0][t], S = u.pr[1][0][t];
      #pragma unroll
      for (int q = 1; q < 16; q++){
        float4 m2 = u.pr[0][q][t], s2 = u.pr[1][q][t];
        M.x = fmaxf(M.x, m2.x); M.y = fmaxf(M.y, m2.y);
        M.z = fmaxf(M.z, m2.z); M.w = fmaxf(M.w, m2.w);
        S.x += s2.x; S.y += s2.y; S.z += s2.z; S.w += s2.w;
      }
      float ki = 1.f/256.f;
      zacc[t*4+0] = M.x; zacc[t*4+1] = M.y; zacc[t*4+2] = M.z; zacc[t*4+3] = M.w;
      zacc[128+t*4+0] = S.x*ki; zacc[128+t*4+1] = S.y*ki;
      zacc[128+t*4+2] = S.z*ki; zacc[128+t*4+3] = S.w*ki;
    }
    __syncthreads();     // pr dead before relabel reuses the union
  }
  relabel<false>(edges, csr, si, u.r.map, u.r.sb, u.r.cur, dl, rpl, cntl,
                 t, 512, 256, gbase, ebase);

  // ================= level 2: GEMM (in-place) + gather-hp =================
  gemm_inplace(xl, W2, 256, t);
  {
    float4 bb = ((const float4*)b2)[l];
    float4 wp = ((const float4*)Wp)[l];
    for (int r = 0; r < 16; r++){
      int n = r*16 + j0;
      float4 acc = row_edges_coh(csr, rpl[n], cntl[n], xl4, gbase, l);
      float di = dl[n], dd = di*di;
      float4 hs = xl4[n*32 + l];
      float4 v;
      v.x = fmaxf(acc.x + hs.x*dd + bb.x, 0.f);
      v.y = fmaxf(acc.y + hs.y*dd + bb.y, 0.f);
      v.z = fmaxf(acc.z + hs.z*dd + bb.z, 0.f);
      v.w = fmaxf(acc.w + hs.w*dd + bb.w, 0.f);
      float contrib = v.x*wp.x + v.y*wp.y + v.z*wp.z + v.w*wp.w;
      #pragma unroll
      for (int off = 16; off; off >>= 1) contrib += __shfl_down(contrib, off, 32);
      if (l == 0) hpl[n] = contrib;
    }
  }
  __syncthreads();

  // ================= M2: level-2 mega (256 -> 128) =================
  {
    float v = 0.f;
    if (t < 256){
      float a = score_edges<true>(csr, rpl[t], cntl[t], hpl, gbase);
      float di = dl[t];
      v = tanhf(a + hpl[t]*di*di + bp0);
    }
    bitonic_sort(sv, si, v, t, t, 256, t < 256);
  }
  {
    float4 bb = ((const float4*)b2)[l];
    float4 o[8];
    float4 mx = make_float4(-INFINITY,-INFINITY,-INFINITY,-INFINITY);
    float4 sm = make_float4(0.f,0.f,0.f,0.f);
    #pragma unroll
    for (int r = 0; r < 8; r++){
      int j = j0 + 16*r;
      float val = sv[j]; int row = si[j];
      float4 acc = row_edges_coh(csr, rpl[row], cntl[row], xl4, gbase, l);
      float di = dl[row], dd = di*di;
      float4 hs = xl4[row*32 + l];
      float4 v;
      v.x = fmaxf(acc.x + hs.x*dd + bb.x, 0.f);
      v.y = fmaxf(acc.y + hs.y*dd + bb.y, 0.f);
      v.z = fmaxf(acc.z + hs.z*dd + bb.z, 0.f);
      v.w = fmaxf(acc.w + hs.w*dd + bb.w, 0.f);
      float4 ov = make_float4(v.x*val, v.y*val, v.z*val, v.w*val);
      o[r] = ov;
      mx.x = fmaxf(mx.x, ov.x); mx.y = fmaxf(mx.y, ov.y);
      mx.z = fmaxf(mx.z, ov.z); mx.w = fmaxf(mx.w, ov.w);
      sm.x += ov.x; sm.y += ov.y; sm.z += ov.z; sm.w += ov.w;
    }
    u.pr[0][j0][l] = mx; u.pr[1][j0][l] = sm;
    __syncthreads();                      // all h2 reads done
    #pragma unroll
    for (int r = 0; r < 8; r++){ int j = j0 + 16*r; xl4[j*32 + l] = o[r]; }
    if (t < 32){
      float4 M = u.pr[0][0][t], S = u.pr[1][0][t];
      #pragma unroll
      for (int q = 1; q < 16; q++){
        float4 m2 = u.pr[0][q][t], s2 = u.pr[1][q][t];
        M.x = fmaxf(M.x, m2.x); M.y = fmaxf(M.y, m2.y);
        M.z = fmaxf(M.z, m2.z); M.w = fmaxf(M.w, m2.w);
        S.x += s2.x; S.y += s2.y; S.z += s2.z; S.w += s2.w;
      }
      float ki = 1.f/128.f;
      zacc[t*4+0] += M.x; zacc[t*4+1] += M.y; zacc[t*4+2] += M.z; zacc[t*4+3] += M.w;
      zacc[128+t*4+0] += S.x*ki; zacc[128+t*4+1] += S.y*ki;
      zacc[128+t*4+2] += S.z*ki; zacc[128+t*4+3] += S.w*ki;
    }
    __syncthreads();
  }
  relabel<true>(edges, csr, si, u.r.map, u.r.sb, u.r.cur, dl, rpl, cntl,
                t, 256, 128, gbase, ebase);

  // ================= level 3: GEMM (in-place) + gather-hp =================
  gemm_inplace(xl, W3, 128, t);
  {
    float4 bb = ((const float4*)b3)[l];
    float4 wp = ((const float4*)Wp)[l];
    for (int r = 0; r < 8; r++){
      int n = r*16 + j0;
      float4 acc = row_edges_coh(csr, rpl[n], cntl[n], xl4, gbase, l);
      float di = dl[n], dd = di*di;
      float4 hs = xl4[n*32 + l];
      float4 v;
      v.x = fmaxf(acc.x + hs.x*dd + bb.x, 0.f);
      v.y = fmaxf(acc.y + hs.y*dd + bb.y, 0.f);
      v.z = fmaxf(acc.z + hs.z*dd + bb.z, 0.f);
      v.w = fmaxf(acc.w + hs.w*dd + bb.w, 0.f);
      float contrib = v.x*wp.x + v.y*wp.y + v.z*wp.z + v.w*wp.w;
      #pragma unroll
      for (int off = 16; off; off >>= 1) contrib += __shfl_down(contrib, off, 32);
      if (l == 0) hpl[n] = contrib;
    }
  }
  __syncthreads();

  // ================= M3: level-3 mega (128 -> 64) + MLP =================
  {
    float v = 0.f;
    if (t < 128){
      float a = score_edges<true>(csr, rpl[t], cntl[t], hpl, gbase);
      float di = dl[t];
      v = tanhf(a + hpl[t]*di*di + bp0);
    }
    bitonic_sort(sv, si, v, t, t, 128, t < 128);
  }
  {
    float4 bb = ((const float4*)b3)[l];
    float4 mx = make_float4(-INFINITY,-INFINITY,-INFINITY,-INFINITY);
    float4 sm = make_float4(0.f,0.f,0.f,0.f);
    #pragma unroll
    for (int r = 0; r < 4; r++){
      int j = j0 + 16*r;
      float val = sv[j]; int row = si[j];
      float4 acc = row_edges_coh(csr, rpl[row], cntl[row], xl4, gbase, l);
      float di = dl[row], dd = di*di;
      float4 hs = xl4[row*32 + l];
      float4 v;
      v.x = fmaxf(acc.x + hs.x*dd + bb.x, 0.f);
      v.y = fmaxf(acc.y + hs.y*dd + bb.y, 0.f);
      v.z = fmaxf(acc.z + hs.z*dd + bb.z, 0.f);
      v.w = fmaxf(acc.w + hs.w*dd + bb.w, 0.f);
      float4 ov = make_float4(v.x*val, v.y*val, v.z*val, v.w*val);
      mx.x = fmaxf(mx.x, ov.x); mx.y = fmaxf(mx.y, ov.y);
      mx.z = fmaxf(mx.z, ov.z); mx.w = fmaxf(mx.w, ov.w);
      sm.x += ov.x; sm.y += ov.y; sm.z += ov.z; sm.w += ov.w;
    }
    u.pr[0][j0][l] = mx; u.pr[1][j0][l] = sm;
    __syncthreads();
    if (t < 32){
      float4 M = u.pr[0][0][t], S = u.pr[1][0][t];
      #pragma unroll
      for (int q = 1; q < 16; q++){
        float4 m2 = u.pr[0][q][t], s2 = u.pr[1][q][t];
        M.x = fmaxf(M.x, m2.x); M.y = fmaxf(M.y, m2.y);
        M.z = fmaxf(M.z, m2.z); M.w = fmaxf(M.w, m2.w);
        S.x += s2.x; S.y += s2.y; S.z += s2.z; S.w += s2.w;
      }
      float ki = 1.f/64.f;
      zacc[t*4+0] += M.x; zacc[t*4+1] += M.y; zacc[t*4+2] += M.z; zacc[t*4+3] += M.w;
      zacc[128+t*4+0] += S.x*ki; zacc[128+t*4+1] += S.y*ki;
      zacc[128+t*4+2] += S.z*ki; zacc[128+t*4+3] += S.w*ki;
    }
    __syncthreads();
  }
  // MLP + log_softmax (sv reused as h1, hpl as h2)
  if (t < 128){
    float a = L1b[t];
    for (int i = 0; i < 256; i++) a += zacc[i]*L1W[i*128 + t];
    sv[t] = fmaxf(a, 0.f);
  }
  __syncthreads();
  if (t < 64){
    float a = L2b[t];
    for (int i = 0; i < 128; i++) a += sv[i]*L2W[i*64 + t];
    hpl[t] = fmaxf(a, 0.f);
  }
  __syncthreads();
  if (t == 0){
    float mxv = -INFINITY;
    for (int i = 0; i < 64; i++) mxv = fmaxf(mxv, hpl[i]);
    float s = 0.f;
    for (int i = 0; i < 64; i++) s += expf(hpl[i] - mxv);
    red[0] = mxv; red[1] = logf(s);
  }
  __syncthreads();
  if (t < 64) out[g*64 + t] = hpl[t] - red[0] - red[1];
}

extern "C" void kernel_launch(void* const* d_in, const int* in_sizes, int n_in,
                              void* d_out, int out_size, void* d_ws, size_t ws_size,
                              hipStream_t stream){
  (void)in_sizes; (void)n_in; (void)out_size; (void)ws_size;
  const float* x0  = (const float*)d_in[0];
  const int*   s0  = (const int*)  d_in[1];
  const int*   d0  = (const int*)  d_in[2];
  const float* W1  = (const float*)d_in[3];  const float* b1 = (const float*)d_in[4];
  const float* W2  = (const float*)d_in[5];  const float* b2 = (const float*)d_in[6];
  const float* W3  = (const float*)d_in[7];  const float* b3 = (const float*)d_in[8];
  const float* Wp  = (const float*)d_in[9];  const float* bp = (const float*)d_in[10];
  const float* L1W = (const float*)d_in[11]; const float* L1b = (const float*)d_in[12];
  const float* L2W = (const float*)d_in[13]; const float* L2b = (const float*)d_in[14];
  float* out = (float*)d_out;

  // workspace layout (elements)
  float* w = (float*)d_ws;
  float* gout  = w; w += 32768*HID;          // level-1 GCN output (read by tail)
  float* dinvv = w; w += 32768;              // level-1 dinv
  float* hppt  = w; w += 4*32768;            // level-1 hp quarter-partials
  int* cnt     = (int*)w; w += 32768;
  int* rowptr  = (int*)w; w += 32768;
  int2* edges  = (int2*)w; w += 2*E_TOT;
  int2* csr    = (int2*)w; w += 2*E_TOT;

  k_topo0<<<BGR, 512, 0, stream>>>(s0, d0, edges, cnt, rowptr, dinvv, csr);
  k_l1_fused<<<512, 512, 65536, stream>>>(x0, W1, csr, rowptr, cnt, dinvv,
                                          b1, Wp, (float4*)gout, hppt);
  k_tail<<<BGR, 512, 0, stream>>>((const float4*)gout, hppt, csr, edges,
                                  rowptr, cnt, dinvv, bp, W2, b2, W3, b3, Wp,
                                  L1W, L1b, L2W, L2b, out);
}